// Round 9
// baseline (618.659 us; speedup 1.0000x reference)
//
#include <hip/hip_runtime.h>

// Persistent LSTM: N=4096, T=256, IN=2, E=64, H=128, OUT=2.
// 512 blocks x 512 threads (8 waves); block b owns batch rows [8b,8b+8).
// amdgpu_waves_per_eu(4,4) -> reg budget 128/wave (VGPR+AGPR, r6 lesson) ->
// TWO blocks co-resident per CU with INDEPENDENT barriers (phase overlap).
// Register diet vs r2 (which needed ~144):
//  - rows duplicated into tile rows 8-15: EW = 2 cells/lane on ALL 64 lanes
//    (14 trans vs 28), no zero-padding maintenance.
//  - embed path in bf8 e5m2 (low-magnitude path; err ~0.002 on gate preacts):
//    W_ih frags 16 VGPR, embed acts in bf8 LDS ping-pong, bf8_bf8 MFMA.
//  - W_hh k-tile 3 B-frags in LDS (32KB/block), read per step (-16 VGPR).
//  - y-proj = per-thread bf16 dot + shfl reduce on waves 0-3 (no fy frags);
//    embed compute on waves 4-7 (straggler balance).
// Per wave/step: 8 bf8 + 20 bf16 MFMA... (24 total), 14 trans, 1 barrier.

#define T_LEN 256

typedef __attribute__((ext_vector_type(8))) short short8;
typedef __attribute__((ext_vector_type(4))) float f32x4;
typedef __attribute__((ext_vector_type(2))) float f32x2;
typedef unsigned long long u64;

__device__ __forceinline__ unsigned short f2bf(float f) {
  unsigned u = __builtin_bit_cast(unsigned, f);
  u += 0x7fffu + ((u >> 16) & 1u);           // RNE
  return (unsigned short)(u >> 16);
}
__device__ __forceinline__ float bf2f(unsigned short h) {
  unsigned u = ((unsigned)h) << 16;
  return __builtin_bit_cast(float, u);
}
__device__ __forceinline__ unsigned char f2bf8(float f) {   // e5m2, RNE via f16
  _Float16 hf = (_Float16)f;
  unsigned short hu = __builtin_bit_cast(unsigned short, hf);
  hu = (unsigned short)(hu + 0x7f + ((hu >> 8) & 1u));
  return (unsigned char)(hu >> 8);
}
__device__ __forceinline__ f32x2 exp2v(f32x2 x) {
  return (f32x2){__builtin_amdgcn_exp2f(x[0]), __builtin_amdgcn_exp2f(x[1])};
}
__device__ __forceinline__ f32x2 rcpv(f32x2 x) {
  return (f32x2){__builtin_amdgcn_rcpf(x[0]), __builtin_amdgcn_rcpf(x[1])};
}
// fused LSTM cell on 2 rows (14 trans total)
__device__ __forceinline__ f32x2 ewpair(f32x2 i, f32x2 f, f32x2 g, f32x2 o, f32x2& c) {
  const float K1 = -1.4426950408889634f, K2 = -2.8853900817779268f;
  f32x2 ei = exp2v(i * K1);
  f32x2 ef = exp2v(f * K1);
  f32x2 eg = exp2v(g * K2);
  f32x2 eo = exp2v(o * K1);
  f32x2 t1 = ei + 1.f, tf = ef + 1.f, t2 = eg + 1.f, t3 = 1.f - eg, to = eo + 1.f;
  f32x2 q1 = t1 * t2;
  f32x2 num = c * q1 + t3 * tf;
  f32x2 cn = num * rcpv(q1 * tf);
  c = cn;
  f32x2 cc = __builtin_elementwise_min(
      __builtin_elementwise_max(cn, (f32x2){-20.f, -20.f}), (f32x2){20.f, 20.f});
  f32x2 ec = exp2v(cc * K2);
  return (1.f - ec) * rcpv(to * (ec + 1.f));
}
__device__ __forceinline__ short8 packbf8v(const float* src) {
  float4 lo = *(const float4*)src;
  float4 hi = *(const float4*)(src + 4);
  short8 f;
  f[0] = (short)f2bf(lo.x); f[1] = (short)f2bf(lo.y);
  f[2] = (short)f2bf(lo.z); f[3] = (short)f2bf(lo.w);
  f[4] = (short)f2bf(hi.x); f[5] = (short)f2bf(hi.y);
  f[6] = (short)f2bf(hi.z); f[7] = (short)f2bf(hi.w);
  return f;
}
__device__ __forceinline__ u64 pack8bf8(const float* src) {
  u64 r = 0;
  #pragma unroll
  for (int j = 0; j < 8; ++j) r |= ((u64)f2bf8(src[j])) << (8 * j);
  return r;
}

#define MFMA16 __builtin_amdgcn_mfma_f32_16x16x32_bf16
#define MFMA8  __builtin_amdgcn_mfma_f32_16x16x32_bf8_bf8

__global__ void __attribute__((amdgpu_flat_work_group_size(512, 512),
                               amdgpu_waves_per_eu(4, 4)))
lstm_persist(
    const float* __restrict__ x,    const float* __restrict__ W_in,
    const float* __restrict__ b_in, const float* __restrict__ W_ih,
    const float* __restrict__ W_hh, const float* __restrict__ b_ih,
    const float* __restrict__ b_hh, const float* __restrict__ W_out,
    const float* __restrict__ b_out, float* __restrict__ out)
{
  __shared__ __align__(16) float xsT[2 * T_LEN][8];            // 16 KB
  __shared__ __align__(16) unsigned short Abuf[2][16 * 136];   // 8.7 KB h bf16 (dup rows)
  __shared__ __align__(16) unsigned char  embB[2][16 * 72];    // 2.25 KB embed bf8 (dup)
  __shared__ __align__(16) unsigned short WhhL[8 * 4 * 64 * 8];// 32 KB W_hh kt3 B-frags
  __shared__ __align__(16) unsigned short woutS[256];          // W_out bf16
  __shared__ float WinS[128];
  __shared__ float binS[64];
  __shared__ float boutS[2];

  const int tid = threadIdx.x;
  const int w   = tid >> 6;
  const int l   = tid & 63;
  const int l15 = l & 15;
  const int lq  = l >> 4;
  const int u   = w * 16 + l15;

  // ---- stage x transposed (8 rows x 512 floats) ----
  const float* xg = x + (size_t)blockIdx.x * (8 * 2 * T_LEN);
  #pragma unroll
  for (int i = tid; i < 1024; i += 512) {
    float4 v = ((const float4*)xg)[i];
    int fi = i * 4, r = fi >> 9, c0 = fi & 511;
    xsT[c0][r] = v.x; xsT[c0 + 1][r] = v.y; xsT[c0 + 2][r] = v.z; xsT[c0 + 3][r] = v.w;
  }
  if (tid < 128) WinS[tid]  = W_in[tid];
  if (tid < 64)  binS[tid]  = b_in[tid];
  if (tid < 256) woutS[tid] = f2bf(W_out[tid]);
  if (tid < 2)   boutS[tid] = b_out[tid];

  // ---- weights: W_hh kt0-2 bf16 regs, kt3 -> LDS; W_ih bf8 regs; bias ----
  short8 fbH[4][3];
  u64    fbI[4][2];
  float  bias[4];
  #pragma unroll
  for (int g = 0; g < 4; ++g) {
    const int grow = g * 128 + u;
    bias[g] = b_ih[grow] + b_hh[grow];
    #pragma unroll
    for (int kt = 0; kt < 3; ++kt)
      fbH[g][kt] = packbf8v(W_hh + grow * 128 + kt * 32 + lq * 8);
    *(short8*)&WhhL[((w * 4 + g) * 64 + l) * 8] =
        packbf8v(W_hh + grow * 128 + 96 + lq * 8);
    fbI[g][0] = pack8bf8(W_ih + grow * 64 + 0 * 32 + lq * 8);
    fbI[g][1] = pack8bf8(W_ih + grow * 64 + 1 * 32 + lq * 8);
  }
  __syncthreads();   // xsT, LDS weights ready

  // ---- zero h buffer 0; embed e0 -> embB[0] ----
  for (int i = tid; i < 1088; i += 512)
    ((unsigned*)&Abuf[0][0])[i] = 0u;
  if (tid < 256) {
    const int r = tid >> 5, e0 = (tid & 31) * 2;
    const float x0 = xsT[0][r], x1 = xsT[1][r];
    float v0 = fmaf(x1, WinS[2 * e0 + 1], fmaf(x0, WinS[2 * e0], binS[e0]));
    float v1 = fmaf(x1, WinS[2 * e0 + 3], fmaf(x0, WinS[2 * e0 + 2], binS[e0 + 1]));
    v0 = v0 > 0.f ? v0 : 0.f; v1 = v1 > 0.f ? v1 : 0.f;
    const unsigned short pk = (unsigned short)(f2bf8(v0) | (f2bf8(v1) << 8));
    *(unsigned short*)&embB[0][r * 72 + e0] = pk;
    *(unsigned short*)&embB[0][(r + 8) * 72 + e0] = pk;
  }
  __syncthreads();

  f32x2 c2 = {0.f, 0.f};
  const int qb    = (lq & 2);               // acc slots {qb, qb+1}
  const int row_a = (lq & 1) * 4 + (lq & 2); // rows {row_a, row_a+1}
  const size_t obase = (size_t)blockIdx.x * (8 * 2 * T_LEN);
  // y-proj / embed thread mappings
  const int yr = (tid & 255) >> 5, ypo = (tid >> 4) & 1, ypl = tid & 15;
  const int er = (tid & 255) >> 5, ee0 = (tid & 31) * 2;

  for (int t = 0; t < T_LEN; ++t) {
    const int p = t & 1;
    const unsigned short* bR = &Abuf[p][0];
    unsigned short*       bW = &Abuf[p ^ 1][0];
    const unsigned char*  eR = &embB[p][0];
    unsigned char*        eW = &embB[p ^ 1][0];

    // loads
    const u64 ea0 = *(const u64*)&eR[l15 * 72 + 0 * 32 + lq * 8];
    const u64 ea1 = *(const u64*)&eR[l15 * 72 + 1 * 32 + lq * 8];
    const short8 ah0 = *(const short8*)&bR[l15 * 136 + 0 * 32 + lq * 8];
    const short8 ah1 = *(const short8*)&bR[l15 * 136 + 1 * 32 + lq * 8];
    const short8 ah2 = *(const short8*)&bR[l15 * 136 + 2 * 32 + lq * 8];
    const short8 ah3 = *(const short8*)&bR[l15 * 136 + 3 * 32 + lq * 8];

    f32x4 acc[4];
    #pragma unroll
    for (int g = 0; g < 4; ++g) {
      f32x4 s = (f32x4){bias[g], bias[g], bias[g], bias[g]};
      s = MFMA8((long)ea0, (long)fbI[g][0], s, 0, 0, 0);
      s = MFMA8((long)ea1, (long)fbI[g][1], s, 0, 0, 0);
      acc[g] = s;
    }
    #pragma unroll
    for (int kt = 0; kt < 3; ++kt) {
      const short8 ah = (kt == 0) ? ah0 : (kt == 1) ? ah1 : ah2;
      #pragma unroll
      for (int g = 0; g < 4; ++g)
        acc[g] = MFMA16(ah, fbH[g][kt], acc[g], 0, 0, 0);
    }
    #pragma unroll
    for (int g = 0; g < 4; ++g) {
      const short8 wb = *(const short8*)&WhhL[((w * 4 + g) * 64 + l) * 8];
      acc[g] = MFMA16(ah3, wb, acc[g], 0, 0, 0);
    }

    // y_{t-1} on waves 0-3: per-thread bf16 dot over 8 units + shfl reduce
    if (tid < 256 && t > 0) {
      const short8 hv = *(const short8*)&bR[yr * 136 + ypl * 8];
      const short8 wv = *(const short8*)&woutS[ypo * 128 + ypl * 8];
      float s = 0.f;
      #pragma unroll
      for (int j = 0; j < 8; ++j)
        s = fmaf(bf2f((unsigned short)hv[j]), bf2f((unsigned short)wv[j]), s);
      s += __shfl_xor(s, 1);
      s += __shfl_xor(s, 2);
      s += __shfl_xor(s, 4);
      s += __shfl_xor(s, 8);
      if (ypl == 0)
        out[obase + (size_t)yr * (2 * T_LEN) + 2 * (t - 1) + ypo] =
            s + boutS[ypo] + xsT[2 * (t - 1) + ypo][yr];
    }

    // EW: 2 cells (rows row_a, row_a+1), all 64 lanes
    {
      f32x2 iv = {acc[0][qb], acc[0][qb + 1]};
      f32x2 fv = {acc[1][qb], acc[1][qb + 1]};
      f32x2 gv = {acc[2][qb], acc[2][qb + 1]};
      f32x2 ov = {acc[3][qb], acc[3][qb + 1]};
      f32x2 hv = ewpair(iv, fv, gv, ov, c2);
      unsigned hp;
      asm("v_cvt_pk_bf16_f32 %0, %1, %2" : "=v"(hp) : "v"(hv[0]), "v"(hv[1]));
      const int b0 = row_a * 136 + u;
      bW[b0]              = (unsigned short)hp;         // row_a
      bW[b0 + 136]        = (unsigned short)(hp >> 16); // row_a+1
      bW[b0 + 8 * 136]    = (unsigned short)hp;         // dup row_a+8
      bW[b0 + 9 * 136]    = (unsigned short)(hp >> 16); // dup row_a+9
    }

    // embed e_{t+1} on waves 4-7 (bf8, dup rows)
    if (tid >= 256 && t + 1 < T_LEN) {
      const int te = t + 1;
      const float x0 = xsT[2 * te][er], x1 = xsT[2 * te + 1][er];
      float v0 = fmaf(x1, WinS[2 * ee0 + 1], fmaf(x0, WinS[2 * ee0], binS[ee0]));
      float v1 = fmaf(x1, WinS[2 * ee0 + 3], fmaf(x0, WinS[2 * ee0 + 2], binS[ee0 + 1]));
      v0 = v0 > 0.f ? v0 : 0.f; v1 = v1 > 0.f ? v1 : 0.f;
      const unsigned short pk = (unsigned short)(f2bf8(v0) | (f2bf8(v1) << 8));
      *(unsigned short*)&eW[er * 72 + ee0] = pk;
      *(unsigned short*)&eW[(er + 8) * 72 + ee0] = pk;
    }

    __syncthreads();   // ONE barrier per step
  }

  // epilogue: y_255 from h_256 (in Abuf[0])
  if (tid < 256) {
    const unsigned short* hb = &Abuf[0][0];
    const short8 hv = *(const short8*)&hb[yr * 136 + ypl * 8];
    const short8 wv = *(const short8*)&woutS[ypo * 128 + ypl * 8];
    float s = 0.f;
    #pragma unroll
    for (int j = 0; j < 8; ++j)
      s = fmaf(bf2f((unsigned short)hv[j]), bf2f((unsigned short)wv[j]), s);
    s += __shfl_xor(s, 1);
    s += __shfl_xor(s, 2);
    s += __shfl_xor(s, 4);
    s += __shfl_xor(s, 8);
    if (ypl == 0)
      out[obase + (size_t)yr * (2 * T_LEN) + 2 * 255 + ypo] =
          s + boutS[ypo] + xsT[2 * 255 + ypo][yr];
  }
}

extern "C" void kernel_launch(void* const* d_in, const int* in_sizes, int n_in,
                              void* d_out, int out_size, void* d_ws, size_t ws_size,
                              hipStream_t stream) {
  const float* x     = (const float*)d_in[0];
  const float* W_in  = (const float*)d_in[1];
  const float* b_in  = (const float*)d_in[2];
  const float* W_ih  = (const float*)d_in[3];
  const float* W_hh  = (const float*)d_in[4];
  const float* b_ih  = (const float*)d_in[5];
  const float* b_hh  = (const float*)d_in[6];
  const float* W_out = (const float*)d_in[7];
  const float* b_out = (const float*)d_in[8];
  float* out = (float*)d_out;

  lstm_persist<<<dim3(512), dim3(512), 0, stream>>>(
      x, W_in, b_in, W_ih, W_hh, b_ih, b_hh, W_out, b_out, out);
}

// Round 10
// 267.076 us; speedup vs baseline: 2.3164x; 2.3164x over previous
//
#include <hip/hip_runtime.h>

// Persistent LSTM: N=4096, T=256, IN=2, E=64, H=128, OUT=2.
// 256 blocks x 512 threads (8 waves), block b owns rows [16b,16b+16).
// Consolidated r2 structure (best: 262us) + issue-work cuts:
//  - amdgpu_waves_per_eu(2,2): honest 256-reg budget (r2 was capped at 128
//    while needing ~190 -> rematerialization VALU overhead; r3-r9 proved
//    >=3 waves/SIMD is structurally unreachable for this weight-stationary
//    design: ~150-200 regs/wave incl AGPR).
//  - MFMA dep-chain split: per gate, h-part kt2,3 chain on the pre-issued
//    embed acc; kt4,5 on an independent zero acc; merged with packed adds.
//  - v_cvt_pk_bf16_f32 for h/embed stores; embed = one b32 store/thread.
//  - y-proj round-robin (wave t&7, fbY in regs) - kills fyB LDS reads
//    (8-way bank conflict) and spreads global-store latency.
// 3 rotating A-buffers, embed 2 steps ahead, 1 barrier/step.

#define T_LEN 256
#define ROWS  16
#define ASTR  200

typedef __attribute__((ext_vector_type(8))) short short8;
typedef __attribute__((ext_vector_type(4))) float f32x4;
typedef __attribute__((ext_vector_type(2))) float f32x2;

__device__ __forceinline__ unsigned short f2bf(float f) {
  unsigned u = __builtin_bit_cast(unsigned, f);
  u += 0x7fffu + ((u >> 16) & 1u);           // RNE
  return (unsigned short)(u >> 16);
}
__device__ __forceinline__ f32x2 exp2v(f32x2 x) {
  return (f32x2){__builtin_amdgcn_exp2f(x[0]), __builtin_amdgcn_exp2f(x[1])};
}
__device__ __forceinline__ f32x2 rcpv(f32x2 x) {
  return (f32x2){__builtin_amdgcn_rcpf(x[0]), __builtin_amdgcn_rcpf(x[1])};
}

// fused LSTM cell on 2 rows: sig(x)=1/(1+2^(K1 x)), tanh=(1-2^(K2 x))/(1+2^(K2 x))
__device__ __forceinline__ f32x2 ewpair(f32x2 i, f32x2 f, f32x2 g, f32x2 o, f32x2& c) {
  const float K1 = -1.4426950408889634f, K2 = -2.8853900817779268f;
  f32x2 ei = exp2v(i * K1);
  f32x2 ef = exp2v(f * K1);
  f32x2 eg = exp2v(g * K2);
  f32x2 eo = exp2v(o * K1);
  f32x2 t1 = ei + 1.f, tf = ef + 1.f, t2 = eg + 1.f, t3 = 1.f - eg, to = eo + 1.f;
  f32x2 q1 = t1 * t2;
  f32x2 num = c * q1 + t3 * tf;
  f32x2 cn = num * rcpv(q1 * tf);
  c = cn;
  f32x2 cc = __builtin_elementwise_min(
      __builtin_elementwise_max(cn, (f32x2){-20.f, -20.f}), (f32x2){20.f, 20.f});
  f32x2 ec = exp2v(cc * K2);
  return (1.f - ec) * rcpv(to * (ec + 1.f));
}

__device__ __forceinline__ short8 packbf8(const float* src) {
  float4 lo = *(const float4*)src;
  float4 hi = *(const float4*)(src + 4);
  short8 f;
  f[0] = (short)f2bf(lo.x); f[1] = (short)f2bf(lo.y);
  f[2] = (short)f2bf(lo.z); f[3] = (short)f2bf(lo.w);
  f[4] = (short)f2bf(hi.x); f[5] = (short)f2bf(hi.y);
  f[6] = (short)f2bf(hi.z); f[7] = (short)f2bf(hi.w);
  return f;
}

#define MFMA __builtin_amdgcn_mfma_f32_16x16x32_bf16

__global__ void __attribute__((amdgpu_flat_work_group_size(512, 512),
                               amdgpu_waves_per_eu(2, 2)))
lstm_persist(
    const float* __restrict__ x,    const float* __restrict__ W_in,
    const float* __restrict__ b_in, const float* __restrict__ W_ih,
    const float* __restrict__ W_hh, const float* __restrict__ b_ih,
    const float* __restrict__ b_hh, const float* __restrict__ W_out,
    const float* __restrict__ b_out, float* __restrict__ out)
{
  __shared__ __align__(16) float xsT[2 * T_LEN][ROWS];           // 32 KB
  __shared__ __align__(16) unsigned short Abuf[3][ROWS][ASTR];   // 18.75 KB
  __shared__ float WinS[128];
  __shared__ float binS[64];

  const int tid  = threadIdx.x;
  const int w    = tid >> 6;
  const int l    = tid & 63;
  const int l15  = l & 15;
  const int lq   = l >> 4;
  const int u    = w * 16 + l15;
  const int row0 = lq * 4;

  // ---- stage x transposed ----
  const float* xg = x + (size_t)blockIdx.x * ROWS * 2 * T_LEN;
  #pragma unroll
  for (int i = tid; i < ROWS * 2 * T_LEN / 4; i += 512) {
    float4 v = ((const float4*)xg)[i];
    int fi = i * 4, r = fi >> 9, c0 = fi & 511;
    xsT[c0][r] = v.x; xsT[c0 + 1][r] = v.y; xsT[c0 + 2][r] = v.z; xsT[c0 + 3][r] = v.w;
  }
  if (tid < 128) WinS[tid] = W_in[tid];
  if (tid < 64)  binS[tid] = b_in[tid];

  // ---- gate weight fragments (96 VGPR) + scalar bias ----
  short8 fb[4][6];
  float  bias[4];
  #pragma unroll
  for (int g = 0; g < 4; ++g) {
    const int grow = g * 128 + u;
    bias[g] = b_ih[grow] + b_hh[grow];
    #pragma unroll
    for (int kt = 0; kt < 6; ++kt) {
      const int kk = kt * 32 + lq * 8;
      const float* src = (kk < 64) ? (W_ih + grow * 64 + kk)
                                   : (W_hh + grow * 128 + (kk - 64));
      fb[g][kt] = packbf8(src);
    }
  }
  // y-proj fragments in registers on ALL waves (round-robin straggler spread)
  short8 fbY[4];
  #pragma unroll
  for (int kt = 0; kt < 4; ++kt) {
    short8 fy = {0, 0, 0, 0, 0, 0, 0, 0};
    if (l15 < 2) fy = packbf8(W_out + l15 * 128 + kt * 32 + lq * 8);
    fbY[kt] = fy;
  }
  const float bout_r = (l15 < 2) ? b_out[l15] : 0.f;

  __syncthreads();   // xsT, WinS, binS ready

  auto embed_to = [&](unsigned short (*buf)[ASTR], int t) {
    const int r  = tid >> 5;
    const int e0 = (tid & 31) * 2;
    const float x0 = xsT[2 * t][r], x1 = xsT[2 * t + 1][r];
    float v0 = fmaf(x1, WinS[2 * e0 + 1], fmaf(x0, WinS[2 * e0], binS[e0]));
    float v1 = fmaf(x1, WinS[2 * e0 + 3], fmaf(x0, WinS[2 * e0 + 2], binS[e0 + 1]));
    v0 = v0 > 0.f ? v0 : 0.f;
    v1 = v1 > 0.f ? v1 : 0.f;
    unsigned ep;
    asm("v_cvt_pk_bf16_f32 %0, %1, %2" : "=v"(ep) : "v"(v0), "v"(v1));
    *(unsigned*)&buf[r][e0] = ep;
  };

  // h0 = 0 in buf0; embeds e0 -> buf0, e1 -> buf1
  for (int i = tid; i < ROWS * 128; i += 512)
    Abuf[0][i >> 7][64 + (i & 127)] = 0;
  embed_to(Abuf[0], 0);
  embed_to(Abuf[1], 1);
  __syncthreads();

  // seed accA with bias + embed-part MFMAs for t=0
  f32x4 accA[4], accB[4];
  {
    const short8 a0 = *(const short8*)&Abuf[0][l15][lq * 8];
    const short8 a1 = *(const short8*)&Abuf[0][l15][32 + lq * 8];
    #pragma unroll
    for (int g = 0; g < 4; ++g) {
      f32x4 acc = (f32x4){bias[g], bias[g], bias[g], bias[g]};
      acc = MFMA(a0, fb[g][0], acc, 0, 0, 0);
      acc = MFMA(a1, fb[g][1], acc, 0, 0, 0);
      accA[g] = acc;
    }
  }

  f32x2 c01 = {0.f, 0.f}, c23 = {0.f, 0.f};
  const size_t obase = (size_t)blockIdx.x * ROWS * 2 * T_LEN;

  auto step = [&](int t, unsigned short (*bR)[ASTR], unsigned short (*bW)[ASTR],
                  unsigned short (*bE)[ASTR], f32x4 (&accC)[4], f32x4 (&accN)[4]) {
    // h-part fragments
    short8 ah[4];
    #pragma unroll
    for (int kt = 0; kt < 4; ++kt)
      ah[kt] = *(const short8*)&bR[l15][(kt + 2) * 32 + lq * 8];

    // split chains: accC (carries bias+embed, 2 deps) || accQ (zero, 2 deps)
    f32x4 accQ[4];
    #pragma unroll
    for (int g = 0; g < 4; ++g) {
      accC[g] = MFMA(ah[0], fb[g][2], accC[g], 0, 0, 0);
      accQ[g] = MFMA(ah[2], fb[g][4], (f32x4){0.f, 0.f, 0.f, 0.f}, 0, 0, 0);
    }
    #pragma unroll
    for (int g = 0; g < 4; ++g) {
      accC[g] = MFMA(ah[1], fb[g][3], accC[g], 0, 0, 0);
      accQ[g] = MFMA(ah[3], fb[g][5], accQ[g], 0, 0, 0);
    }

    // y_{t-1} = h_t @ W_out^T + b_out + x_{t-1}  (wave t&7, lag-1)
    const int yw = t & 7;
    f32x4 accY;
    if (w == yw) {
      const int tt = t ? t - 1 : 0;
      #pragma unroll
      for (int q = 0; q < 4; ++q)
        accY[q] = (l15 < 2) ? (bout_r + xsT[2 * tt + l15][lq * 4 + q]) : 0.f;
      accY = MFMA(ah[0], fbY[0], accY, 0, 0, 0);
      accY = MFMA(ah[1], fbY[1], accY, 0, 0, 0);
      accY = MFMA(ah[2], fbY[2], accY, 0, 0, 0);
      accY = MFMA(ah[3], fbY[3], accY, 0, 0, 0);
    }

    // pre-issue next step's embed-part MFMAs (e_{t+1} resident in bW since t-1)
    if (t + 1 < T_LEN) {
      const short8 a0 = *(const short8*)&bW[l15][lq * 8];
      const short8 a1 = *(const short8*)&bW[l15][32 + lq * 8];
      #pragma unroll
      for (int g = 0; g < 4; ++g) {
        f32x4 acc = (f32x4){bias[g], bias[g], bias[g], bias[g]};
        acc = MFMA(a0, fb[g][0], acc, 0, 0, 0);
        acc = MFMA(a1, fb[g][1], acc, 0, 0, 0);
        accN[g] = acc;
      }
    }

    // merge split chains
    #pragma unroll
    for (int g = 0; g < 4; ++g)
      accC[g] += accQ[g];

    // elementwise (fused-exp, packed pairs) -> h_{t+1} into bW
    {
      f32x2 i01 = {accC[0][0], accC[0][1]}, f01 = {accC[1][0], accC[1][1]};
      f32x2 g01 = {accC[2][0], accC[2][1]}, o01 = {accC[3][0], accC[3][1]};
      f32x2 h01 = ewpair(i01, f01, g01, o01, c01);
      unsigned hp;
      asm("v_cvt_pk_bf16_f32 %0, %1, %2" : "=v"(hp) : "v"(h01[0]), "v"(h01[1]));
      bW[row0 + 0][64 + u] = (unsigned short)hp;
      bW[row0 + 1][64 + u] = (unsigned short)(hp >> 16);
      f32x2 i23 = {accC[0][2], accC[0][3]}, f23 = {accC[1][2], accC[1][3]};
      f32x2 g23 = {accC[2][2], accC[2][3]}, o23 = {accC[3][2], accC[3][3]};
      f32x2 h23 = ewpair(i23, f23, g23, o23, c23);
      unsigned hq;
      asm("v_cvt_pk_bf16_f32 %0, %1, %2" : "=v"(hq) : "v"(h23[0]), "v"(h23[1]));
      bW[row0 + 2][64 + u] = (unsigned short)hq;
      bW[row0 + 3][64 + u] = (unsigned short)(hq >> 16);
    }

    // embed e_{t+2} -> bE
    if (t + 2 < T_LEN) embed_to(bE, t + 2);

    // write y_{t-1}
    if (w == yw && t > 0 && l15 < 2) {
      #pragma unroll
      for (int q = 0; q < 4; ++q)
        out[obase + (size_t)(lq * 4 + q) * (2 * T_LEN) + 2 * (t - 1) + l15] = accY[q];
    }

    __syncthreads();   // the ONE barrier per step
  };

  unsigned short (*B0)[ASTR] = Abuf[0];
  unsigned short (*B1)[ASTR] = Abuf[1];
  unsigned short (*B2)[ASTR] = Abuf[2];

  for (int t = 0; t < 252; t += 6) {
    step(t + 0, B0, B1, B2, accA, accB);
    step(t + 1, B1, B2, B0, accB, accA);
    step(t + 2, B2, B0, B1, accA, accB);
    step(t + 3, B0, B1, B2, accB, accA);
    step(t + 4, B1, B2, B0, accA, accB);
    step(t + 5, B2, B0, B1, accB, accA);
  }
  step(252, B0, B1, B2, accA, accB);
  step(253, B1, B2, B0, accB, accA);
  step(254, B2, B0, B1, accA, accB);
  step(255, B0, B1, B2, accB, accA);

  // epilogue: y_255 = h_256 @ W_out^T + b_out + x_255 ; h_256 is in Abuf[1]
  if (w == 0) {
    short8 ah[4];
    #pragma unroll
    for (int kt = 0; kt < 4; ++kt)
      ah[kt] = *(const short8*)&Abuf[1][l15][(kt + 2) * 32 + lq * 8];
    f32x4 accY;
    #pragma unroll
    for (int q = 0; q < 4; ++q)
      accY[q] = (l15 < 2) ? (bout_r + xsT[2 * 255 + l15][lq * 4 + q]) : 0.f;
    accY = MFMA(ah[0], fbY[0], accY, 0, 0, 0);
    accY = MFMA(ah[1], fbY[1], accY, 0, 0, 0);
    accY = MFMA(ah[2], fbY[2], accY, 0, 0, 0);
    accY = MFMA(ah[3], fbY[3], accY, 0, 0, 0);
    if (l15 < 2) {
      #pragma unroll
      for (int q = 0; q < 4; ++q)
        out[obase + (size_t)(lq * 4 + q) * (2 * T_LEN) + 2 * 255 + l15] = accY[q];
    }
  }
}

extern "C" void kernel_launch(void* const* d_in, const int* in_sizes, int n_in,
                              void* d_out, int out_size, void* d_ws, size_t ws_size,
                              hipStream_t stream) {
  const float* x     = (const float*)d_in[0];
  const float* W_in  = (const float*)d_in[1];
  const float* b_in  = (const float*)d_in[2];
  const float* W_ih  = (const float*)d_in[3];
  const float* W_hh  = (const float*)d_in[4];
  const float* b_ih  = (const float*)d_in[5];
  const float* b_hh  = (const float*)d_in[6];
  const float* W_out = (const float*)d_in[7];
  const float* b_out = (const float*)d_in[8];
  float* out = (float*)d_out;

  lstm_persist<<<dim3(256), dim3(512), 0, stream>>>(
      x, W_in, b_in, W_ih, W_hh, b_ih, b_hh, W_out, b_out, out);
}